// Round 1
// baseline (1114.071 us; speedup 1.0000x reference)
//
#include <hip/hip_runtime.h>
#include <cstdint>
#include <cstddef>

#define N_NODES 50000
#define N_EDGES 800000
#define HDIM    256
#define NREL    8
#define NSEG    (N_NODES * NREL)      // 400000
#define KDIM    (NREL * HDIM + HDIM)  // 2304 : [mean slices | node_states]
#define LN_EPSF 1e-5f

using short8  = __attribute__((ext_vector_type(8))) short;
using float4v = __attribute__((ext_vector_type(4))) float;

static __device__ __forceinline__ float bf2f(unsigned short u) {
    union { float f; uint32_t i; } v; v.i = ((uint32_t)u) << 16; return v.f;
}
static __device__ __forceinline__ unsigned short f2bf(float f) {
    union { float f; uint32_t i; } v; v.f = f;
    uint32_t r = v.i + 0x7FFFu + ((v.i >> 16) & 1u);   // round-to-nearest-even
    return (unsigned short)(r >> 16);
}

// ---------------- pass 1: count edges per (dst, rel) segment ----------------
__global__ void k_count(const int* __restrict__ ei, const int* __restrict__ et,
                        int* __restrict__ cnt) {
    int e = blockIdx.x * blockDim.x + threadIdx.x;
    if (e >= N_EDGES) return;
    int dst = ei[N_EDGES + e];
    int rel = et[e];
    atomicAdd(&cnt[dst * NREL + rel], 1);
}

// ---------------- pass 2: exclusive scan over 400k segments (1 block) -------
__global__ __launch_bounds__(1024) void k_scan(const int* __restrict__ cnt,
                                               int* __restrict__ off) {
    __shared__ int s[1024];
    int t = threadIdx.x;
    const int CH = (NSEG + 1023) / 1024;  // 391
    int lo = t * CH, hi = lo + CH; if (hi > NSEG) hi = NSEG;
    int sum = 0;
    for (int i = lo; i < hi; ++i) sum += cnt[i];
    s[t] = sum;
    __syncthreads();
    for (int d = 1; d < 1024; d <<= 1) {
        int v = (t >= d) ? s[t - d] : 0;
        __syncthreads();
        s[t] += v;
        __syncthreads();
    }
    int run = s[t] - sum;  // exclusive prefix of this chunk
    for (int i = lo; i < hi; ++i) { off[i] = run; run += cnt[i]; }
    if (t == 1023) off[NSEG] = s[1023];
}

// ---------------- pass 3: scatter edge srcs into segment-sorted order -------
__global__ void k_scatter(const int* __restrict__ ei, const int* __restrict__ et,
                          const int* __restrict__ off, int* __restrict__ cursor,
                          int* __restrict__ srcs) {
    int e = blockIdx.x * blockDim.x + threadIdx.x;
    if (e >= N_EDGES) return;
    int src = ei[e];
    int dst = ei[N_EDGES + e];
    int rel = et[e];
    int seg = dst * NREL + rel;
    int pos = off[seg] + atomicAdd(&cursor[seg], 1);
    srcs[pos] = src;
}

// ---------------- pass 4: per-(node,rel) mean -> bf16 A matrix --------------
// Afull[n][0:2048]  = mean(n, r, :)  (bf16)
// Afull[n][2048:]   = node_states[n] (bf16)   -> root term via fused GEMM
__global__ __launch_bounds__(256) void k_aggregate(const float* __restrict__ ns,
                                                   const int* __restrict__ off,
                                                   const int* __restrict__ srcs,
                                                   unsigned short* __restrict__ Afull) {
    int n = blockIdx.x, t = threadIdx.x;
    size_t arow = (size_t)n * KDIM;
    #pragma unroll
    for (int r = 0; r < NREL; ++r) {
        int seg = n * NREL + r;
        int e0 = off[seg], e1 = off[seg + 1];
        float acc = 0.f;
        for (int e = e0; e < e1; ++e) {
            int src = srcs[e];  // uniform across block -> broadcast
            acc += ns[(size_t)src * HDIM + t];
        }
        int c = e1 - e0;
        float inv = (c > 0) ? 1.0f / (float)c : 0.0f;  // zero-edge buckets stay 0
        Afull[arow + r * HDIM + t] = f2bf(acc * inv);
    }
    Afull[arow + NREL * HDIM + t] = f2bf(ns[(size_t)n * HDIM + t]);
}

// ---------------- pass 5: build transposed bf16 weight matrix ---------------
// Bt[j][k], j = output col in [0,256), k in [0,2304):
//   k < 2048 : W_rel[k>>8][k&255][j] ;  k >= 2048 : W_root[k-2048][j]
__global__ void k_buildB(const float* __restrict__ Wrel, const float* __restrict__ Wroot,
                         unsigned short* __restrict__ Bt) {
    int idx = blockIdx.x * blockDim.x + threadIdx.x;
    if (idx >= HDIM * KDIM) return;
    int j = idx / KDIM;
    int k = idx % KDIM;
    float v;
    if (k < NREL * HDIM) {
        int r = k >> 8, h = k & 255;
        v = Wrel[((size_t)r * HDIM + h) * HDIM + j];
    } else {
        int h = k - NREL * HDIM;
        v = Wroot[(size_t)h * HDIM + j];
    }
    Bt[idx] = f2bf(v);
}

// ---------------- pass 6: bf16 MFMA GEMM  C[M,256] = A[M,2304] x B ----------
#define BM 128
#define BN 128
#define BK 32

__global__ __launch_bounds__(256) void k_gemm(const unsigned short* __restrict__ A,
                                              const unsigned short* __restrict__ Bt,
                                              float* __restrict__ C, int M) {
    __shared__ __align__(16) unsigned short As[BM * BK];  // 8 KB
    __shared__ __align__(16) unsigned short Bs[BN * BK];  // 8 KB

    int tid  = threadIdx.x;
    int lane = tid & 63;
    int wid  = tid >> 6;
    int wm   = wid >> 1, wn = wid & 1;     // 2x2 waves over 128x128 tile
    int brow = blockIdx.x * BM;
    int bcol = blockIdx.y * BN;

    float4v acc[4][4] = {};

    const char* Ab = (const char*)A;
    const char* Bb = (const char*)Bt;
    const size_t rstride = (size_t)KDIM * 2;  // 4608 B row stride for both A and Bt

    for (int kt = 0; kt < KDIM; kt += BK) {
        // ---- stage tiles via global_load_lds width 16 (wave-uniform LDS base) ----
        #pragma unroll
        for (int i = 0; i < 2; ++i) {
            int linear = i * 4096 + wid * 1024 + lane * 16;  // byte offset in tile
            int row = linear >> 6;       // 64 B per row (32 bf16)
            int kb  = linear & 63;
            int ra = brow + row; if (ra > M - 1) ra = M - 1;   // clamp OOB rows
            const char* ga = Ab + (size_t)ra * rstride + (size_t)(kt * 2 + kb);
            __builtin_amdgcn_global_load_lds(
                (const __attribute__((address_space(1))) void*)ga,
                (__attribute__((address_space(3))) void*)((char*)As + i * 4096 + wid * 1024),
                16, 0, 0);
            int rb = bcol + row;  // Nout = 256, exact multiple of BN: no OOB
            const char* gb = Bb + (size_t)rb * rstride + (size_t)(kt * 2 + kb);
            __builtin_amdgcn_global_load_lds(
                (const __attribute__((address_space(1))) void*)gb,
                (__attribute__((address_space(3))) void*)((char*)Bs + i * 4096 + wid * 1024),
                16, 0, 0);
        }
        __syncthreads();

        // ---- LDS -> fragments -> MFMA ----
        short8 a[4], b[4];
        #pragma unroll
        for (int m = 0; m < 4; ++m) {
            int r = wm * 64 + m * 16 + (lane & 15);
            a[m] = *(const short8*)((const char*)As + r * 64 + (lane >> 4) * 16);
        }
        #pragma unroll
        for (int n = 0; n < 4; ++n) {
            int r = wn * 64 + n * 16 + (lane & 15);
            b[n] = *(const short8*)((const char*)Bs + r * 64 + (lane >> 4) * 16);
        }
        #pragma unroll
        for (int m = 0; m < 4; ++m)
            #pragma unroll
            for (int n = 0; n < 4; ++n)
                acc[m][n] = __builtin_amdgcn_mfma_f32_16x16x32_bf16(a[m], b[n], acc[m][n], 0, 0, 0);

        __syncthreads();
    }

    // ---- epilogue: fp32 conv into d_out (C/D map: row=(lane>>4)*4+q, col=lane&15) ----
    #pragma unroll
    for (int m = 0; m < 4; ++m) {
        #pragma unroll
        for (int n = 0; n < 4; ++n) {
            int col = bcol + wn * 64 + n * 16 + (lane & 15);
            #pragma unroll
            for (int q = 0; q < 4; ++q) {
                int row = brow + wm * 64 + m * 16 + (lane >> 4) * 4 + q;
                if (row < M) C[(size_t)row * HDIM + col] = acc[m][n][q];
            }
        }
    }
}

// ---------------- pass 7: bias + exact GELU + residual + LayerNorm ----------
__global__ __launch_bounds__(256) void k_final(const float* __restrict__ ns,
                                               const float* __restrict__ bias,
                                               const float* __restrict__ gamma,
                                               const float* __restrict__ beta,
                                               float* __restrict__ out) {
    int n = blockIdx.x, t = threadIdx.x;
    size_t idx = (size_t)n * HDIM + t;
    float conv = out[idx] + bias[t];
    float g = 0.5f * conv * (1.0f + erff(conv * 0.70710678118654752f));  // exact GELU
    float x = g + ns[idx];  // residual uses fp32 node_states

    float s1 = x, s2 = x * x;
    #pragma unroll
    for (int o = 32; o > 0; o >>= 1) {
        s1 += __shfl_xor(s1, o, 64);
        s2 += __shfl_xor(s2, o, 64);
    }
    __shared__ float r1[4], r2[4];
    if ((t & 63) == 0) { r1[t >> 6] = s1; r2[t >> 6] = s2; }
    __syncthreads();
    s1 = r1[0] + r1[1] + r1[2] + r1[3];
    s2 = r2[0] + r2[1] + r2[2] + r2[3];
    float mu  = s1 * (1.0f / HDIM);
    float var = s2 * (1.0f / HDIM) - mu * mu;
    out[idx] = gamma[t] * (x - mu) * rsqrtf(var + LN_EPSF) + beta[t];
}

extern "C" void kernel_launch(void* const* d_in, const int* in_sizes, int n_in,
                              void* d_out, int out_size, void* d_ws, size_t ws_size,
                              hipStream_t stream) {
    const float* ns    = (const float*)d_in[0];
    const int*   ei    = (const int*)d_in[1];   // [2, E] : src row then dst row
    const int*   et    = (const int*)d_in[2];   // [E]
    const float* Wrel  = (const float*)d_in[3]; // [R, H, H]
    const float* Wroot = (const float*)d_in[4]; // [H, H]
    const float* bias  = (const float*)d_in[5];
    const float* gamma = (const float*)d_in[6];
    const float* beta  = (const float*)d_in[7];
    float* out = (float*)d_out;

    char* w = (char*)d_ws;
    auto take = [&](size_t bytes) -> char* {
        char* p = w; w += (bytes + 255) & ~(size_t)255; return p;
    };
    int* cnt             = (int*)take((size_t)NSEG * 4);
    int* segoff          = (int*)take((size_t)(NSEG + 1) * 4);
    int* cursor          = (int*)take((size_t)NSEG * 4);
    int* srcs            = (int*)take((size_t)N_EDGES * 4);
    unsigned short* Afull = (unsigned short*)take((size_t)N_NODES * KDIM * 2);
    unsigned short* Bt    = (unsigned short*)take((size_t)HDIM * KDIM * 2);

    hipMemsetAsync(cnt, 0, (size_t)NSEG * 4, stream);
    hipMemsetAsync(cursor, 0, (size_t)NSEG * 4, stream);

    k_count<<<(N_EDGES + 255) / 256, 256, 0, stream>>>(ei, et, cnt);
    k_scan<<<1, 1024, 0, stream>>>(cnt, segoff);
    k_scatter<<<(N_EDGES + 255) / 256, 256, 0, stream>>>(ei, et, segoff, cursor, srcs);
    k_aggregate<<<N_NODES, 256, 0, stream>>>(ns, segoff, srcs, Afull);
    k_buildB<<<(HDIM * KDIM + 255) / 256, 256, 0, stream>>>(Wrel, Wroot, Bt);

    dim3 gg((N_NODES + BM - 1) / BM, HDIM / BN);
    k_gemm<<<gg, 256, 0, stream>>>(Afull, Bt, out, N_NODES);

    k_final<<<N_NODES, 256, 0, stream>>>(ns, bias, gamma, beta, out);
}

// Round 2
// 478.355 us; speedup vs baseline: 2.3290x; 2.3290x over previous
//
#include <hip/hip_runtime.h>
#include <cstdint>
#include <cstddef>

#define N_NODES 50000
#define N_EDGES 800000
#define HDIM    256
#define NREL    8
#define NSEG    (N_NODES * NREL)      // 400000
#define KDIM    (NREL * HDIM + HDIM)  // 2304 : [mean slices | node_states]
#define LN_EPSF 1e-5f

#define SCAN_CHUNK 1024
#define SCAN_NB    ((NSEG + SCAN_CHUNK - 1) / SCAN_CHUNK)   // 391

using short8  = __attribute__((ext_vector_type(8))) short;
using float4v = __attribute__((ext_vector_type(4))) float;

static __device__ __forceinline__ unsigned short f2bf(float f) {
    union { float f; uint32_t i; } v; v.f = f;
    uint32_t r = v.i + 0x7FFFu + ((v.i >> 16) & 1u);   // round-to-nearest-even
    return (unsigned short)(r >> 16);
}

// ---------------- pass 1: count edges per (dst, rel) segment ----------------
__global__ void k_count(const int* __restrict__ ei, const int* __restrict__ et,
                        int* __restrict__ cnt) {
    int e = blockIdx.x * blockDim.x + threadIdx.x;
    if (e >= N_EDGES) return;
    int dst = ei[N_EDGES + e];
    int rel = et[e];
    atomicAdd(&cnt[dst * NREL + rel], 1);
}

// ---------------- pass 2a: per-chunk sums (coalesced int4) ------------------
__global__ __launch_bounds__(256) void k_scan1(const int* __restrict__ cnt,
                                               int* __restrict__ bsum) {
    int b = blockIdx.x, t = threadIdx.x;
    int idx = b * SCAN_CHUNK + t * 4;
    int4 v = {0, 0, 0, 0};
    if (idx + 3 < NSEG) v = *(const int4*)&cnt[idx];
    else {
        #pragma unroll
        for (int j = 0; j < 4; ++j) if (idx + j < NSEG) ((int*)&v)[j] = cnt[idx + j];
    }
    int s = v.x + v.y + v.z + v.w;
    #pragma unroll
    for (int o = 32; o > 0; o >>= 1) s += __shfl_xor(s, o, 64);
    __shared__ int ls[4];
    if ((t & 63) == 0) ls[t >> 6] = s;
    __syncthreads();
    if (t == 0) bsum[b] = ls[0] + ls[1] + ls[2] + ls[3];
}

// ---------------- pass 2b: scan the 391 block sums (1 tiny block) -----------
__global__ __launch_bounds__(512) void k_scan2(const int* __restrict__ bsum,
                                               int* __restrict__ boff) {
    __shared__ int s[512];
    int t = threadIdx.x;
    int v = (t < SCAN_NB) ? bsum[t] : 0;
    s[t] = v;
    __syncthreads();
    for (int d = 1; d < 512; d <<= 1) {
        int x = (t >= d) ? s[t - d] : 0;
        __syncthreads();
        s[t] += x;
        __syncthreads();
    }
    if (t < SCAN_NB) boff[t] = s[t] - v;  // exclusive prefix of block sums
}

// ---------------- pass 2c: in-chunk exclusive scan + block offset -----------
__global__ __launch_bounds__(256) void k_scan3(const int* __restrict__ cnt,
                                               const int* __restrict__ boff,
                                               int* __restrict__ off) {
    int b = blockIdx.x, t = threadIdx.x;
    int idx = b * SCAN_CHUNK + t * 4;
    int4 v = {0, 0, 0, 0};
    if (idx + 3 < NSEG) v = *(const int4*)&cnt[idx];
    else {
        #pragma unroll
        for (int j = 0; j < 4; ++j) if (idx + j < NSEG) ((int*)&v)[j] = cnt[idx + j];
    }
    int s = v.x + v.y + v.z + v.w;
    __shared__ int ls[256];
    ls[t] = s;
    __syncthreads();
    for (int d = 1; d < 256; d <<= 1) {
        int x = (t >= d) ? ls[t - d] : 0;
        __syncthreads();
        ls[t] += x;
        __syncthreads();
    }
    int run = boff[b] + ls[t] - s;  // exclusive prefix for this thread's 4 elems
    int4 w;
    w.x = run; run += v.x;
    w.y = run; run += v.y;
    w.z = run; run += v.z;
    w.w = run;
    if (idx + 3 < NSEG) *(int4*)&off[idx] = w;
    else {
        #pragma unroll
        for (int j = 0; j < 4; ++j) if (idx + j < NSEG) off[idx + j] = ((int*)&w)[j];
    }
    if (b == 0 && t == 0) off[NSEG] = N_EDGES;  // total count is exactly E
}

// ---------------- pass 3: scatter edge srcs into segment-sorted order -------
__global__ void k_scatter(const int* __restrict__ ei, const int* __restrict__ et,
                          const int* __restrict__ off, int* __restrict__ cursor,
                          int* __restrict__ srcs) {
    int e = blockIdx.x * blockDim.x + threadIdx.x;
    if (e >= N_EDGES) return;
    int src = ei[e];
    int dst = ei[N_EDGES + e];
    int rel = et[e];
    int seg = dst * NREL + rel;
    int pos = off[seg] + atomicAdd(&cursor[seg], 1);
    srcs[pos] = src;
}

// ---------------- pass 4: per-(node,rel) mean -> bf16 A matrix --------------
// Afull[n][0:2048]  = mean(n, r, :)  (bf16)
// Afull[n][2048:]   = node_states[n] (bf16)   -> root term via fused GEMM
__global__ __launch_bounds__(256) void k_aggregate(const float* __restrict__ ns,
                                                   const int* __restrict__ off,
                                                   const int* __restrict__ srcs,
                                                   unsigned short* __restrict__ Afull) {
    int n = blockIdx.x, t = threadIdx.x;
    size_t arow = (size_t)n * KDIM;
    #pragma unroll
    for (int r = 0; r < NREL; ++r) {
        int seg = n * NREL + r;
        int e0 = off[seg], e1 = off[seg + 1];
        float acc = 0.f;
        for (int e = e0; e < e1; ++e) {
            int src = srcs[e];  // uniform across block -> broadcast
            acc += ns[(size_t)src * HDIM + t];
        }
        int c = e1 - e0;
        float inv = (c > 0) ? 1.0f / (float)c : 0.0f;  // zero-edge buckets stay 0
        Afull[arow + r * HDIM + t] = f2bf(acc * inv);
    }
    Afull[arow + NREL * HDIM + t] = f2bf(ns[(size_t)n * HDIM + t]);
}

// ---------------- pass 5: build transposed bf16 weight matrix ---------------
// Bt[j][k], j = output col in [0,256), k in [0,2304):
//   k < 2048 : W_rel[k>>8][k&255][j] ;  k >= 2048 : W_root[k-2048][j]
__global__ void k_buildB(const float* __restrict__ Wrel, const float* __restrict__ Wroot,
                         unsigned short* __restrict__ Bt) {
    int idx = blockIdx.x * blockDim.x + threadIdx.x;
    if (idx >= HDIM * KDIM) return;
    int j = idx / KDIM;
    int k = idx % KDIM;
    float v;
    if (k < NREL * HDIM) {
        int r = k >> 8, h = k & 255;
        v = Wrel[((size_t)r * HDIM + h) * HDIM + j];
    } else {
        int h = k - NREL * HDIM;
        v = Wroot[(size_t)h * HDIM + j];
    }
    Bt[idx] = f2bf(v);
}

// ---------------- pass 6: bf16 MFMA GEMM  C[M,256] = A[M,2304] x B ----------
#define BM 128
#define BN 128
#define BK 32

__global__ __launch_bounds__(256) void k_gemm(const unsigned short* __restrict__ A,
                                              const unsigned short* __restrict__ Bt,
                                              float* __restrict__ C, int M) {
    __shared__ __align__(16) unsigned short As[BM * BK];  // 8 KB
    __shared__ __align__(16) unsigned short Bs[BN * BK];  // 8 KB

    int tid  = threadIdx.x;
    int lane = tid & 63;
    int wid  = tid >> 6;
    int wm   = wid >> 1, wn = wid & 1;     // 2x2 waves over 128x128 tile
    int brow = blockIdx.x * BM;
    int bcol = blockIdx.y * BN;

    float4v acc[4][4] = {};

    const char* Ab = (const char*)A;
    const char* Bb = (const char*)Bt;
    const size_t rstride = (size_t)KDIM * 2;  // 4608 B row stride for both A and Bt

    for (int kt = 0; kt < KDIM; kt += BK) {
        // ---- stage tiles via global_load_lds width 16 (wave-uniform LDS base) ----
        #pragma unroll
        for (int i = 0; i < 2; ++i) {
            int linear = i * 4096 + wid * 1024 + lane * 16;  // byte offset in tile
            int row = linear >> 6;       // 64 B per row (32 bf16)
            int kb  = linear & 63;
            int ra = brow + row; if (ra > M - 1) ra = M - 1;   // clamp OOB rows
            const char* ga = Ab + (size_t)ra * rstride + (size_t)(kt * 2 + kb);
            __builtin_amdgcn_global_load_lds(
                (const __attribute__((address_space(1))) void*)ga,
                (__attribute__((address_space(3))) void*)((char*)As + i * 4096 + wid * 1024),
                16, 0, 0);
            int rb = bcol + row;  // Nout = 256, exact multiple of BN: no OOB
            const char* gb = Bb + (size_t)rb * rstride + (size_t)(kt * 2 + kb);
            __builtin_amdgcn_global_load_lds(
                (const __attribute__((address_space(1))) void*)gb,
                (__attribute__((address_space(3))) void*)((char*)Bs + i * 4096 + wid * 1024),
                16, 0, 0);
        }
        __syncthreads();

        // ---- LDS -> fragments -> MFMA ----
        short8 a[4], b[4];
        #pragma unroll
        for (int m = 0; m < 4; ++m) {
            int r = wm * 64 + m * 16 + (lane & 15);
            a[m] = *(const short8*)((const char*)As + r * 64 + (lane >> 4) * 16);
        }
        #pragma unroll
        for (int n = 0; n < 4; ++n) {
            int r = wn * 64 + n * 16 + (lane & 15);
            b[n] = *(const short8*)((const char*)Bs + r * 64 + (lane >> 4) * 16);
        }
        #pragma unroll
        for (int m = 0; m < 4; ++m)
            #pragma unroll
            for (int n = 0; n < 4; ++n)
                acc[m][n] = __builtin_amdgcn_mfma_f32_16x16x32_bf16(a[m], b[n], acc[m][n], 0, 0, 0);

        __syncthreads();
    }

    // ---- epilogue: fp32 conv into d_out (C/D map: row=(lane>>4)*4+q, col=lane&15) ----
    #pragma unroll
    for (int m = 0; m < 4; ++m) {
        #pragma unroll
        for (int n = 0; n < 4; ++n) {
            int col = bcol + wn * 64 + n * 16 + (lane & 15);
            #pragma unroll
            for (int q = 0; q < 4; ++q) {
                int row = brow + wm * 64 + m * 16 + (lane >> 4) * 4 + q;
                if (row < M) C[(size_t)row * HDIM + col] = acc[m][n][q];
            }
        }
    }
}

// ---------------- pass 7: bias + exact GELU + residual + LayerNorm ----------
__global__ __launch_bounds__(256) void k_final(const float* __restrict__ ns,
                                               const float* __restrict__ bias,
                                               const float* __restrict__ gamma,
                                               const float* __restrict__ beta,
                                               float* __restrict__ out) {
    int n = blockIdx.x, t = threadIdx.x;
    size_t idx = (size_t)n * HDIM + t;
    float conv = out[idx] + bias[t];
    float g = 0.5f * conv * (1.0f + erff(conv * 0.70710678118654752f));  // exact GELU
    float x = g + ns[idx];  // residual uses fp32 node_states

    float s1 = x, s2 = x * x;
    #pragma unroll
    for (int o = 32; o > 0; o >>= 1) {
        s1 += __shfl_xor(s1, o, 64);
        s2 += __shfl_xor(s2, o, 64);
    }
    __shared__ float r1[4], r2[4];
    if ((t & 63) == 0) { r1[t >> 6] = s1; r2[t >> 6] = s2; }
    __syncthreads();
    s1 = r1[0] + r1[1] + r1[2] + r1[3];
    s2 = r2[0] + r2[1] + r2[2] + r2[3];
    float mu  = s1 * (1.0f / HDIM);
    float var = s2 * (1.0f / HDIM) - mu * mu;
    out[idx] = gamma[t] * (x - mu) * rsqrtf(var + LN_EPSF) + beta[t];
}

extern "C" void kernel_launch(void* const* d_in, const int* in_sizes, int n_in,
                              void* d_out, int out_size, void* d_ws, size_t ws_size,
                              hipStream_t stream) {
    const float* ns    = (const float*)d_in[0];
    const int*   ei    = (const int*)d_in[1];   // [2, E] : src row then dst row
    const int*   et    = (const int*)d_in[2];   // [E]
    const float* Wrel  = (const float*)d_in[3]; // [R, H, H]
    const float* Wroot = (const float*)d_in[4]; // [H, H]
    const float* bias  = (const float*)d_in[5];
    const float* gamma = (const float*)d_in[6];
    const float* beta  = (const float*)d_in[7];
    float* out = (float*)d_out;

    char* w = (char*)d_ws;
    auto take = [&](size_t bytes) -> char* {
        char* p = w; w += (bytes + 255) & ~(size_t)255; return p;
    };
    int* cnt              = (int*)take((size_t)NSEG * 4);
    int* segoff           = (int*)take((size_t)(NSEG + 1) * 4);
    int* cursor           = (int*)take((size_t)NSEG * 4);
    int* srcs             = (int*)take((size_t)N_EDGES * 4);
    int* bsum             = (int*)take((size_t)SCAN_NB * 4);
    int* boff             = (int*)take((size_t)SCAN_NB * 4);
    unsigned short* Afull = (unsigned short*)take((size_t)N_NODES * KDIM * 2);
    unsigned short* Bt    = (unsigned short*)take((size_t)HDIM * KDIM * 2);

    hipMemsetAsync(cnt, 0, (size_t)NSEG * 4, stream);
    hipMemsetAsync(cursor, 0, (size_t)NSEG * 4, stream);

    k_count<<<(N_EDGES + 255) / 256, 256, 0, stream>>>(ei, et, cnt);
    k_scan1<<<SCAN_NB, 256, 0, stream>>>(cnt, bsum);
    k_scan2<<<1, 512, 0, stream>>>(bsum, boff);
    k_scan3<<<SCAN_NB, 256, 0, stream>>>(cnt, boff, segoff);
    k_scatter<<<(N_EDGES + 255) / 256, 256, 0, stream>>>(ei, et, segoff, cursor, srcs);
    k_aggregate<<<N_NODES, 256, 0, stream>>>(ns, segoff, srcs, Afull);
    k_buildB<<<(HDIM * KDIM + 255) / 256, 256, 0, stream>>>(Wrel, Wroot, Bt);

    dim3 gg((N_NODES + BM - 1) / BM, HDIM / BN);
    k_gemm<<<gg, 256, 0, stream>>>(Afull, Bt, out, N_NODES);

    k_final<<<N_NODES, 256, 0, stream>>>(ns, bias, gamma, beta, out);
}